// Round 7
// baseline (674.446 us; speedup 1.0000x reference)
//
#include <hip/hip_runtime.h>

// LePEAttention: B=16, H=W=64, C=384, HEADS=12, hd=32, IDX=0 (vertical strips).
// Pipeline R11: k_prep (cvt x->x16 + lepe) -> k_qkv (R9: 256x128 dbuf 2-phase)
//               -> k_attnproj (fused attn + proj, NOW software-pipelined).
// MFMA layouts (HW-verified): A[m=lane&15][k=quad*8+j]; B mirrored;
//   C/D: col=lane&15, row=quad*4+reg.
// R11 (attnproj only; rest identical): R10 measured attnproj 138us at 2.0 TB/s
//   (31% of achievable BW), MfmaUtil 7.4%, 4.9M LDS bank conflicts ->
//   HBM-latency-bound, low memory-level parallelism.
//   1) prefetch next head's 12 qkv loads during current head's attn (ping-pong regs)
//   2) prefetch next proj-chunk's lepe+pw loads during current chunk's MFMA
//   3) vt XOR-swizzle (dg rows alias mod-32 banks at stride 72) write+read
//   4) s_setprio(1) around MFMA clusters.

typedef _Float16 f16;
typedef _Float16 f16x2 __attribute__((ext_vector_type(2)));
typedef _Float16 f16x8 __attribute__((ext_vector_type(8)));
typedef float    f32x4 __attribute__((ext_vector_type(4)));

__device__ __forceinline__ f32x4 mfma_16x16x32(f16x8 a, f16x8 b, f32x4 c) {
  return __builtin_amdgcn_mfma_f32_16x16x32_f16(a, b, c, 0, 0, 0);
}

// async global->LDS 16B copy (dest must be wave-uniform base + lane*16)
__device__ __forceinline__ void gl_lds16(const f16* g, f16* l) {
  __builtin_amdgcn_global_load_lds((const __attribute__((address_space(1))) void*)g,
                                   (__attribute__((address_space(3))) void*)l, 16, 0, 0);
}

// ---------------- fp32 -> fp16 convert (weights) ----------------
__global__ __launch_bounds__(256) void k_cvt(const float* __restrict__ src,
                                             f16* __restrict__ dst, int n8) {
  int i = blockIdx.x * 256 + threadIdx.x;
  if (i >= n8) return;
  const f32x4* s4 = (const f32x4*)src;
  f32x4 a = s4[2 * i], b = s4[2 * i + 1];
  f16x8 o;
#pragma unroll
  for (int j = 0; j < 4; ++j) { o[j] = (f16)a[j]; o[4 + j] = (f16)b[j]; }
  *(f16x8*)&dst[(long)i * 8] = o;
}

// ---------------- fused cvt(x) + LePE conv ----------------
__global__ __launch_bounds__(256) void k_prep(const float* __restrict__ x,
                                              const float* __restrict__ lw,
                                              const float* __restrict__ lb,
                                              f16* __restrict__ x16,
                                              f16* __restrict__ lepe16) {
  __shared__ float ws[9 * 384];
  __shared__ float bs[384];
  for (int i = threadIdx.x; i < 3456; i += 256) {
    int c = i / 9, tap = i - c * 9;
    ws[tap * 384 + (c & 7) * 48 + (c >> 3)] = lw[i];
  }
  for (int i = threadIdx.x; i < 384; i += 256)
    bs[(i & 7) * 48 + (i >> 3)] = lb[i];
  __syncthreads();

  int chunk = blockIdx.x * 256 + threadIdx.x;
  int token = chunk / 48;
  int c0 = (chunk - token * 48) * 8;
  int cg = c0 >> 3;  // 0..47, stride-1 across lanes
  int b = token >> 12, n = token & 4095, h = n >> 6, w = n & 63;
  const float* xb = x + (long)(b << 12) * 384;

  float a8[8];
#pragma unroll
  for (int cc = 0; cc < 8; ++cc) a8[cc] = bs[cc * 48 + cg];
  f16x8 cv;
#pragma unroll
  for (int ky = 0; ky < 3; ++ky) {
    int hh = h + ky - 1;
    if (hh < 0 || hh > 63) continue;
#pragma unroll
    for (int kx = 0; kx < 3; ++kx) {
      int ww = w + kx - 1;
      if (ww < 0 || ww > 63) continue;
      const float* p = xb + (long)((hh << 6) + ww) * 384 + c0;
      float4 u = *(const float4*)p;
      float4 v = *(const float4*)(p + 4);
      float xs[8] = {u.x, u.y, u.z, u.w, v.x, v.y, v.z, v.w};
      if (ky == 1 && kx == 1) {
#pragma unroll
        for (int cc = 0; cc < 8; ++cc) cv[cc] = (f16)xs[cc];
      }
      int tap = ky * 3 + kx;
#pragma unroll
      for (int cc = 0; cc < 8; ++cc)
        a8[cc] += xs[cc] * ws[tap * 384 + cc * 48 + cg];
    }
  }
  f16x8 o;
#pragma unroll
  for (int cc = 0; cc < 8; ++cc) o[cc] = (f16)a8[cc];
  *(f16x8*)&x16[(long)token * 384 + c0] = cv;
  *(f16x8*)&lepe16[(long)token * 384 + c0] = o;
}

// ---------------- QKV GEMM (R9, unchanged): qkv[perm(t)][1152] = x16 @ w16^T --
__global__ __launch_bounds__(512) void k_qkv(const f16* __restrict__ A,
                                             const f16* __restrict__ Bt,
                                             f16* __restrict__ C) {
  __shared__ alignas(16) f16 smem[49152];
  f16* ebuf = smem;
  const int tid = threadIdx.x;
  const int lane = tid & 63;
  const int wave = tid >> 6;
  const int wr = wave >> 1, wc = wave & 1;
  const int ln = lane & 15, quad = lane >> 4;
  const int bid = blockIdx.x;
  const int xcd = bid & 7;
  const int s = bid >> 3;        // 0..287
  const int mq = s / 9;          // 0..31
  const int mt = xcd * 32 + mq;  // 0..255
  const int nt = s - mq * 9;     // 0..8
  const long m0 = (long)mt * 256;
  const int n0 = nt * 128;

  auto stage = [&](int buf, int k0) {
    f16* Asb = smem + buf * 16384;
    f16* Bsb = smem + 32768 + buf * 8192;
#pragma unroll
    for (int r = 0; r < 4; ++r) {
      int flat = r * 512 + tid;
      int row = flat >> 3, c8 = flat & 7;
      int sc8 = (c8 ^ (row & 7)) * 8;
      gl_lds16(&A[(m0 + row) * 384 + k0 + sc8], &Asb[flat * 8]);
    }
#pragma unroll
    for (int r = 0; r < 2; ++r) {
      int flat = r * 512 + tid;
      int row = flat >> 3, c8 = flat & 7;
      int sc8 = (c8 ^ (row & 7)) * 8;
      gl_lds16(&Bt[(long)(n0 + row) * 384 + k0 + sc8], &Bsb[flat * 8]);
    }
  };

  f32x4 acc[4][4] = {};
  stage(0, 0);
  __syncthreads();
  int cur = 0;
  for (int t = 0; t < 6; ++t) {
    if (t < 5) stage(cur ^ 1, (t + 1) * 64);
    const f16* Ac = smem + cur * 16384;
    const f16* Bc = smem + 32768 + cur * 8192;
#pragma unroll
    for (int ks = 0; ks < 2; ++ks) {
      f16x8 a[4], b[4];
#pragma unroll
      for (int i = 0; i < 4; ++i)
        a[i] = *(const f16x8*)&Ac[(wr * 64 + i * 16 + ln) * 64 +
                                  ((ks * 4 + quad) ^ (ln & 7)) * 8];
#pragma unroll
      for (int j = 0; j < 4; ++j)
        b[j] = *(const f16x8*)&Bc[(wc * 64 + j * 16 + ln) * 64 +
                                  ((ks * 4 + quad) ^ (ln & 7)) * 8];
#pragma unroll
      for (int i = 0; i < 4; ++i)
#pragma unroll
        for (int j = 0; j < 4; ++j)
          acc[i][j] = mfma_16x16x32(a[i], b[j], acc[i][j]);
    }
    __syncthreads();
    cur ^= 1;
  }

  for (int p = 0; p < 2; ++p) {
    if ((wr >> 1) == p) {
      const int lr0 = (wr & 1) * 64;
#pragma unroll
      for (int i = 0; i < 4; ++i)
#pragma unroll
        for (int j = 0; j < 4; ++j)
#pragma unroll
          for (int r = 0; r < 4; ++r)
            ebuf[(lr0 + i * 16 + quad * 4 + r) * 136 + wc * 64 + j * 16 + ln] =
                (f16)acc[i][j][r];
    }
    __syncthreads();
#pragma unroll
    for (int it = 0; it < 4; ++it) {
      int flat = it * 512 + tid;
      int row = flat >> 4;
      int c8 = flat & 15;
      int t = (int)m0 + p * 128 + row;
      int nn = t & 4095;
      long prow = (long)(t & ~4095) + ((nn & 63) << 6) + (nn >> 6);
      *(f16x8*)&C[prow * 1152 + n0 + c8 * 8] =
          *(const f16x8*)&ebuf[row * 136 + c8 * 8];
    }
    __syncthreads();
  }
}

// ---------------- FUSED attention + proj: block = strip, 4 waves ----------------
// Phase 1: per wave, 3 heads, software-pipelined (prefetch head hi+1's qkv
//   loads during head hi's compute). vt stores/reads XOR-swizzled.
// Phase 2: 12 k-chunks, prefetch chunk c+1's lepe+pw during chunk c's MFMA.
__global__ __launch_bounds__(256, 2) void k_attnproj(const f16* __restrict__ qkv,
                                                     const f16* __restrict__ lepe16,
                                                     const f16* __restrict__ pw,
                                                     const float* __restrict__ bias,
                                                     float* __restrict__ outf) {
  __shared__ alignas(16) f16 shp[4][7424];          // 59392 B
  __shared__ alignas(16) f16 aschunk[2][64 * 40];   // 10240 B  (total 69632)
  const int lane = threadIdx.x & 63;
  const int wave = threadIdx.x >> 6;
  const int ln = lane & 15, quad = lane >> 4, q8 = quad * 8;
  const int b = blockIdx.x >> 6, w = blockIdx.x & 63;
  const long sbase = (long)b * 4096 + (long)w * 64;  // first permuted row of strip

  f16* qs = shp[wave];
  f16* ks = shp[wave] + 2560;
  f16* vt = shp[wave] + 5120;
  f16* ps = shp[wave];
  const float qscale = 0.17677669529663687f;  // 32^-0.5

  // per-thread load geometry (invariant across heads)
  const int lrow = lane >> 2;          // token 0..15 within r-group
  const int ldg = (lane & 3) * 8;      // dim group 0,8,16,24
  const int lswz = lane & 3;           // (dim>>3)&7 for vt swizzle

  // parked normalized O: ph{h}[i*4+r] packs dims (ln, 16+ln) of row i*16+quad*4+r
  f16x2 ph0[16], ph1[16], ph2[16];

  // ping-pong qkv prefetch regs
  f16x8 rq[2][4], rk[2][4], rv[2][4];
#pragma unroll
  for (int r = 0; r < 4; ++r) {
    int l = r * 16 + lrow;
    long ta = (sbase + l) * 1152 + (wave * 3) * 32 + ldg;
    rq[0][r] = *(const f16x8*)&qkv[ta];
    rk[0][r] = *(const f16x8*)&qkv[ta + 384];
    rv[0][r] = *(const f16x8*)&qkv[ta + 768];
  }

#pragma unroll
  for (int hi = 0; hi < 3; ++hi) {
    const int hh = wave * 3 + hi;
    const int cb = hi & 1;
    // LDS write from regs (q pre-scaled; vt swizzled scalar stores)
#pragma unroll
    for (int r = 0; r < 4; ++r) {
      int l = r * 16 + lrow;
      f16x8 qv = rq[cb][r];
#pragma unroll
      for (int ii = 0; ii < 8; ++ii) qv[ii] = (f16)((float)qv[ii] * qscale);
      *(f16x8*)&qs[l * 40 + ldg] = qv;
      *(f16x8*)&ks[l * 40 + ldg] = rk[cb][r];
      int g = l >> 3, o = l & 7;
#pragma unroll
      for (int ii = 0; ii < 8; ++ii)
        vt[(ldg + ii) * 72 + (((g ^ lswz) << 3) | o)] = rv[cb][r][ii];
    }
    // prefetch next head's qkv (flies under this head's compute)
    if (hi < 2) {
#pragma unroll
      for (int r = 0; r < 4; ++r) {
        int l = r * 16 + lrow;
        long ta = (sbase + l) * 1152 + (hh + 1) * 32 + ldg;
        rq[cb ^ 1][r] = *(const f16x8*)&qkv[ta];
        rk[cb ^ 1][r] = *(const f16x8*)&qkv[ta + 384];
        rv[cb ^ 1][r] = *(const f16x8*)&qkv[ta + 768];
      }
    }
    // S = Q K^T (64x64, K=32)
    f16x8 aq[4], bk[4];
#pragma unroll
    for (int i = 0; i < 4; ++i) aq[i] = *(const f16x8*)&qs[(i * 16 + ln) * 40 + q8];
#pragma unroll
    for (int j = 0; j < 4; ++j) bk[j] = *(const f16x8*)&ks[(j * 16 + ln) * 40 + q8];
    f32x4 sc[4][4] = {};
    __builtin_amdgcn_s_setprio(1);
#pragma unroll
    for (int i = 0; i < 4; ++i)
#pragma unroll
      for (int j = 0; j < 4; ++j) sc[i][j] = mfma_16x16x32(aq[i], bk[j], sc[i][j]);
    __builtin_amdgcn_s_setprio(0);

    // softmax rows; deferred normalization
    float rs[4][4];
#pragma unroll
    for (int i = 0; i < 4; ++i)
#pragma unroll
      for (int r = 0; r < 4; ++r) {
        float m = -1e30f;
#pragma unroll
        for (int j = 0; j < 4; ++j) m = fmaxf(m, sc[i][j][r]);
#pragma unroll
        for (int off = 1; off < 16; off <<= 1) m = fmaxf(m, __shfl_xor(m, off, 64));
        float sum = 0.f;
#pragma unroll
        for (int j = 0; j < 4; ++j) {
          float p = __expf(sc[i][j][r] - m);
          sc[i][j][r] = p;
          sum += p;
        }
#pragma unroll
        for (int off = 1; off < 16; off <<= 1) sum += __shfl_xor(sum, off, 64);
        rs[i][r] = 1.0f / sum;
      }

    // P -> ps (overlays qs/ks; same-wave in-order DS after aq/bk reads)
#pragma unroll
    for (int i = 0; i < 4; ++i)
#pragma unroll
      for (int j = 0; j < 4; ++j)
#pragma unroll
        for (int r = 0; r < 4; ++r)
          ps[(i * 16 + quad * 4 + r) * 72 + j * 16 + ln] = (f16)sc[i][j][r];

    // O = P V (64x32, K=64); vt reads use matching swizzle
    f32x4 oc[4][2] = {};
#pragma unroll
    for (int k2 = 0; k2 < 2; ++k2) {
      f16x8 ap[4], bv[2];
#pragma unroll
      for (int i = 0; i < 4; ++i)
        ap[i] = *(const f16x8*)&ps[(i * 16 + ln) * 72 + k2 * 32 + q8];
#pragma unroll
      for (int j = 0; j < 2; ++j) {
        int dimj = j * 16 + ln;
        bv[j] = *(const f16x8*)&vt[dimj * 72 +
                                   (((k2 * 4 + quad) ^ ((dimj >> 3) & 7)) << 3)];
      }
      __builtin_amdgcn_s_setprio(1);
#pragma unroll
      for (int i = 0; i < 4; ++i)
#pragma unroll
        for (int j = 0; j < 2; ++j) oc[i][j] = mfma_16x16x32(ap[i], bv[j], oc[i][j]);
      __builtin_amdgcn_s_setprio(0);
    }

    // normalize + park (static indices; hi is unroll-constant)
#pragma unroll
    for (int i = 0; i < 4; ++i)
#pragma unroll
      for (int r = 0; r < 4; ++r) {
        f16x2 pk;
        pk[0] = (f16)(oc[i][0][r] * rs[i][r]);
        pk[1] = (f16)(oc[i][1][r] * rs[i][r]);
        if (hi == 0) ph0[i * 4 + r] = pk;
        else if (hi == 1) ph1[i * 4 + r] = pk;
        else ph2[i * 4 + r] = pk;
      }
  }

  // ---------------- phase 2: proj ----------------
#define WRITECHUNK(BI, PH)                                        \
  {                                                               \
    _Pragma("unroll") for (int i = 0; i < 4; ++i)                 \
        _Pragma("unroll") for (int r = 0; r < 4; ++r) {           \
      int row = i * 16 + quad * 4 + r;                            \
      aschunk[BI][row * 40 + ln] = PH[i * 4 + r][0];              \
      aschunk[BI][row * 40 + 16 + ln] = PH[i * 4 + r][1];         \
    }                                                             \
  }

  if (wave == 0) WRITECHUNK(0, ph0);

  const int ncol0 = wave * 96;
  // prefetch chunk 0's lepe + pw
  f16x8 plv[2][4], pbf[2][6];
#pragma unroll
  for (int i = 0; i < 4; ++i)
    plv[0][i] = *(const f16x8*)&lepe16[(sbase + i * 16 + ln) * 384 + q8];
#pragma unroll
  for (int j = 0; j < 6; ++j)
    pbf[0][j] = *(const f16x8*)&pw[(long)(ncol0 + j * 16 + ln) * 384 + q8];
  __syncthreads();

  f32x4 pacc[4][6] = {};
#pragma unroll
  for (int c = 0; c < 12; ++c) {
    const int cb = c & 1;
    // prefetch next chunk's lepe + pw (flies under this chunk's MFMA)
    if (c + 1 < 12) {
#pragma unroll
      for (int i = 0; i < 4; ++i)
        plv[cb ^ 1][i] =
            *(const f16x8*)&lepe16[(sbase + i * 16 + ln) * 384 + (c + 1) * 32 + q8];
#pragma unroll
      for (int j = 0; j < 6; ++j)
        pbf[cb ^ 1][j] =
            *(const f16x8*)&pw[(long)(ncol0 + j * 16 + ln) * 384 + (c + 1) * 32 + q8];
    }
    if (c + 1 < 12 && (c + 1) / 3 == wave) {
      const int h = (c + 1) % 3;  // unroll-constant -> static array choice
      if (h == 0) WRITECHUNK((c + 1) & 1, ph0)
      else if (h == 1) WRITECHUNK((c + 1) & 1, ph1)
      else WRITECHUNK((c + 1) & 1, ph2)
    }
    const f16* ac = aschunk[cb];
    f16x8 afr[4];
#pragma unroll
    for (int i = 0; i < 4; ++i) {
      f16x8 av = *(const f16x8*)&ac[(i * 16 + ln) * 40 + q8];
      afr[i] = av + plv[cb][i];
    }
    __builtin_amdgcn_s_setprio(1);
#pragma unroll
    for (int i = 0; i < 4; ++i)
#pragma unroll
      for (int j = 0; j < 6; ++j)
        pacc[i][j] = mfma_16x16x32(afr[i], pbf[cb][j], pacc[i][j]);
    __builtin_amdgcn_s_setprio(0);
    __syncthreads();
  }
#undef WRITECHUNK

  // epilogue: 2 passes of 32 rows; LDS transpose (overlay shp) + float4 + bias
  float* ebuf = (float*)&shp[0][0];  // 32 x 388 f32 = 49664 B <= 59392
#pragma unroll
  for (int p = 0; p < 2; ++p) {
    __syncthreads();
#pragma unroll
    for (int ii = 0; ii < 2; ++ii)
#pragma unroll
      for (int j = 0; j < 6; ++j)
#pragma unroll
        for (int r = 0; r < 4; ++r)
          ebuf[(ii * 16 + quad * 4 + r) * 388 + ncol0 + j * 16 + ln] =
              pacc[p * 2 + ii][j][r];
    __syncthreads();
#pragma unroll
    for (int it = 0; it < 12; ++it) {
      int flat = it * 256 + threadIdx.x;  // 0..3071
      int row = flat / 96;                // 0..31
      int c4 = flat - row * 96;           // 0..95
      long gr = sbase + p * 32 + row;
      int col = c4 * 4;
      float4 b4 = *(const float4*)&bias[col];
      float4 o = *(const float4*)&ebuf[row * 388 + col];
      o.x += b4.x; o.y += b4.y; o.z += b4.z; o.w += b4.w;
      *(float4*)&outf[gr * 384 + col] = o;
    }
  }
}

// ---------------- launch ----------------
extern "C" void kernel_launch(void* const* d_in, const int* in_sizes, int n_in,
                              void* d_out, int out_size, void* d_ws, size_t ws_size,
                              hipStream_t stream) {
  const float* x = (const float*)d_in[0];
  const float* qkv_w = (const float*)d_in[1];
  const float* proj_w = (const float*)d_in[2];
  const float* proj_b = (const float*)d_in[3];
  const float* lepe_w = (const float*)d_in[4];
  const float* lepe_b = (const float*)d_in[5];
  float* out = (float*)d_out;

  char* ws = (char*)d_ws;
  f16* w16 = (f16*)(ws + 0);              //     884,736 B
  f16* pw16 = (f16*)(ws + 884736);        //     294,912 B
  f16* x16 = (f16*)(ws + 1179648);        //  50,331,648 B
  f16* lepe16 = (f16*)(ws + 51511296);    //  50,331,648 B
  f16* qkv16 = (f16*)(ws + 101842944);    // 150,994,944 B  (total 252,837,888 B)

  k_cvt<<<216, 256, 0, stream>>>(qkv_w, w16, 55296);
  k_cvt<<<72, 256, 0, stream>>>(proj_w, pw16, 18432);
  k_prep<<<12288, 256, 0, stream>>>(x, lepe_w, lepe_b, x16, lepe16);
  k_qkv<<<2304, 512, 0, stream>>>(x16, w16, qkv16);
  k_attnproj<<<1024, 256, 0, stream>>>(qkv16, lepe16, pw16, proj_b, out);
}

// Round 8
// 441.944 us; speedup vs baseline: 1.5261x; 1.5261x over previous
//
#include <hip/hip_runtime.h>

// LePEAttention: B=16, H=W=64, C=384, HEADS=12, hd=32, IDX=0 (vertical strips).
// Pipeline R12: k_prep (cvt x->x16 + lepe) -> k_qkv (R9: 256x128 dbuf 2-phase)
//               -> k_attnproj (fused attn + proj).
// MFMA layouts (HW-verified): A[m=lane&15][k=quad*8+j]; B mirrored;
//   C/D: col=lane&15, row=quad*4+reg.
// R12: R11 spilled ~120MB/dispatch to scratch (WRITE 98->219MB) from +176 VGPRs
//   of ping-pong prefetch state -> 355us. Revert attnproj to R10 structure and
//   keep only zero-VGPR-cost improvements:
//   1) vt XOR-swizzle (R11-verified: conflicts 4.9M->2.55M, correct)
//   2) lepe prefetch via double-buffered global_load_lds (LDS 69.6->77.8 KB,
//      still 2 blocks/CU; hides 12x ~900cyc HBM latency; ZERO VGPRs)
//   3) s_setprio(1) around MFMA clusters.

typedef _Float16 f16;
typedef _Float16 f16x2 __attribute__((ext_vector_type(2)));
typedef _Float16 f16x8 __attribute__((ext_vector_type(8)));
typedef float    f32x4 __attribute__((ext_vector_type(4)));

__device__ __forceinline__ f32x4 mfma_16x16x32(f16x8 a, f16x8 b, f32x4 c) {
  return __builtin_amdgcn_mfma_f32_16x16x32_f16(a, b, c, 0, 0, 0);
}

// async global->LDS 16B copy (dest must be wave-uniform base + lane*16)
__device__ __forceinline__ void gl_lds16(const f16* g, f16* l) {
  __builtin_amdgcn_global_load_lds((const __attribute__((address_space(1))) void*)g,
                                   (__attribute__((address_space(3))) void*)l, 16, 0, 0);
}

// ---------------- fp32 -> fp16 convert (weights) ----------------
__global__ __launch_bounds__(256) void k_cvt(const float* __restrict__ src,
                                             f16* __restrict__ dst, int n8) {
  int i = blockIdx.x * 256 + threadIdx.x;
  if (i >= n8) return;
  const f32x4* s4 = (const f32x4*)src;
  f32x4 a = s4[2 * i], b = s4[2 * i + 1];
  f16x8 o;
#pragma unroll
  for (int j = 0; j < 4; ++j) { o[j] = (f16)a[j]; o[4 + j] = (f16)b[j]; }
  *(f16x8*)&dst[(long)i * 8] = o;
}

// ---------------- fused cvt(x) + LePE conv ----------------
__global__ __launch_bounds__(256) void k_prep(const float* __restrict__ x,
                                              const float* __restrict__ lw,
                                              const float* __restrict__ lb,
                                              f16* __restrict__ x16,
                                              f16* __restrict__ lepe16) {
  __shared__ float ws[9 * 384];
  __shared__ float bs[384];
  for (int i = threadIdx.x; i < 3456; i += 256) {
    int c = i / 9, tap = i - c * 9;
    ws[tap * 384 + (c & 7) * 48 + (c >> 3)] = lw[i];
  }
  for (int i = threadIdx.x; i < 384; i += 256)
    bs[(i & 7) * 48 + (i >> 3)] = lb[i];
  __syncthreads();

  int chunk = blockIdx.x * 256 + threadIdx.x;
  int token = chunk / 48;
  int c0 = (chunk - token * 48) * 8;
  int cg = c0 >> 3;  // 0..47, stride-1 across lanes
  int b = token >> 12, n = token & 4095, h = n >> 6, w = n & 63;
  const float* xb = x + (long)(b << 12) * 384;

  float a8[8];
#pragma unroll
  for (int cc = 0; cc < 8; ++cc) a8[cc] = bs[cc * 48 + cg];
  f16x8 cv;
#pragma unroll
  for (int ky = 0; ky < 3; ++ky) {
    int hh = h + ky - 1;
    if (hh < 0 || hh > 63) continue;
#pragma unroll
    for (int kx = 0; kx < 3; ++kx) {
      int ww = w + kx - 1;
      if (ww < 0 || ww > 63) continue;
      const float* p = xb + (long)((hh << 6) + ww) * 384 + c0;
      float4 u = *(const float4*)p;
      float4 v = *(const float4*)(p + 4);
      float xs[8] = {u.x, u.y, u.z, u.w, v.x, v.y, v.z, v.w};
      if (ky == 1 && kx == 1) {
#pragma unroll
        for (int cc = 0; cc < 8; ++cc) cv[cc] = (f16)xs[cc];
      }
      int tap = ky * 3 + kx;
#pragma unroll
      for (int cc = 0; cc < 8; ++cc)
        a8[cc] += xs[cc] * ws[tap * 384 + cc * 48 + cg];
    }
  }
  f16x8 o;
#pragma unroll
  for (int cc = 0; cc < 8; ++cc) o[cc] = (f16)a8[cc];
  *(f16x8*)&x16[(long)token * 384 + c0] = cv;
  *(f16x8*)&lepe16[(long)token * 384 + c0] = o;
}

// ---------------- QKV GEMM (R9, unchanged): qkv[perm(t)][1152] = x16 @ w16^T --
__global__ __launch_bounds__(512) void k_qkv(const f16* __restrict__ A,
                                             const f16* __restrict__ Bt,
                                             f16* __restrict__ C) {
  __shared__ alignas(16) f16 smem[49152];
  f16* ebuf = smem;
  const int tid = threadIdx.x;
  const int lane = tid & 63;
  const int wave = tid >> 6;
  const int wr = wave >> 1, wc = wave & 1;
  const int ln = lane & 15, quad = lane >> 4;
  const int bid = blockIdx.x;
  const int xcd = bid & 7;
  const int s = bid >> 3;        // 0..287
  const int mq = s / 9;          // 0..31
  const int mt = xcd * 32 + mq;  // 0..255
  const int nt = s - mq * 9;     // 0..8
  const long m0 = (long)mt * 256;
  const int n0 = nt * 128;

  auto stage = [&](int buf, int k0) {
    f16* Asb = smem + buf * 16384;
    f16* Bsb = smem + 32768 + buf * 8192;
#pragma unroll
    for (int r = 0; r < 4; ++r) {
      int flat = r * 512 + tid;
      int row = flat >> 3, c8 = flat & 7;
      int sc8 = (c8 ^ (row & 7)) * 8;
      gl_lds16(&A[(m0 + row) * 384 + k0 + sc8], &Asb[flat * 8]);
    }
#pragma unroll
    for (int r = 0; r < 2; ++r) {
      int flat = r * 512 + tid;
      int row = flat >> 3, c8 = flat & 7;
      int sc8 = (c8 ^ (row & 7)) * 8;
      gl_lds16(&Bt[(long)(n0 + row) * 384 + k0 + sc8], &Bsb[flat * 8]);
    }
  };

  f32x4 acc[4][4] = {};
  stage(0, 0);
  __syncthreads();
  int cur = 0;
  for (int t = 0; t < 6; ++t) {
    if (t < 5) stage(cur ^ 1, (t + 1) * 64);
    const f16* Ac = smem + cur * 16384;
    const f16* Bc = smem + 32768 + cur * 8192;
#pragma unroll
    for (int ks = 0; ks < 2; ++ks) {
      f16x8 a[4], b[4];
#pragma unroll
      for (int i = 0; i < 4; ++i)
        a[i] = *(const f16x8*)&Ac[(wr * 64 + i * 16 + ln) * 64 +
                                  ((ks * 4 + quad) ^ (ln & 7)) * 8];
#pragma unroll
      for (int j = 0; j < 4; ++j)
        b[j] = *(const f16x8*)&Bc[(wc * 64 + j * 16 + ln) * 64 +
                                  ((ks * 4 + quad) ^ (ln & 7)) * 8];
#pragma unroll
      for (int i = 0; i < 4; ++i)
#pragma unroll
        for (int j = 0; j < 4; ++j)
          acc[i][j] = mfma_16x16x32(a[i], b[j], acc[i][j]);
    }
    __syncthreads();
    cur ^= 1;
  }

  for (int p = 0; p < 2; ++p) {
    if ((wr >> 1) == p) {
      const int lr0 = (wr & 1) * 64;
#pragma unroll
      for (int i = 0; i < 4; ++i)
#pragma unroll
        for (int j = 0; j < 4; ++j)
#pragma unroll
          for (int r = 0; r < 4; ++r)
            ebuf[(lr0 + i * 16 + quad * 4 + r) * 136 + wc * 64 + j * 16 + ln] =
                (f16)acc[i][j][r];
    }
    __syncthreads();
#pragma unroll
    for (int it = 0; it < 4; ++it) {
      int flat = it * 512 + tid;
      int row = flat >> 4;
      int c8 = flat & 15;
      int t = (int)m0 + p * 128 + row;
      int nn = t & 4095;
      long prow = (long)(t & ~4095) + ((nn & 63) << 6) + (nn >> 6);
      *(f16x8*)&C[prow * 1152 + n0 + c8 * 8] =
          *(const f16x8*)&ebuf[row * 136 + c8 * 8];
    }
    __syncthreads();
  }
}

// ---------------- FUSED attention + proj: block = strip, 4 waves ----------------
// Phase 1 (R10 structure + vt swizzle): per wave 3 heads, QK^T -> softmax -> PV,
//   normalized O parked in 48 f16x2 VGPRs.
// Phase 2: 12 k-chunks; lepe panel for chunk c+1 staged via global_load_lds into
//   double-buffered LDS (zero VGPR cost) while chunk c MFMAs; pw direct (L2).
__global__ __launch_bounds__(256, 2) void k_attnproj(const f16* __restrict__ qkv,
                                                     const f16* __restrict__ lepe16,
                                                     const f16* __restrict__ pw,
                                                     const float* __restrict__ bias,
                                                     float* __restrict__ outf) {
  __shared__ alignas(16) f16 shp[4][7424];          // 59392 B
  __shared__ alignas(16) f16 aschunk[2][64 * 40];   // 10240 B
  __shared__ alignas(16) f16 lbuf[2][64 * 32];      //  8192 B (total 77824)
  const int lane = threadIdx.x & 63;
  const int wave = threadIdx.x >> 6;
  const int ln = lane & 15, quad = lane >> 4, q8 = quad * 8;
  const int b = blockIdx.x >> 6, w = blockIdx.x & 63;
  const long sbase = (long)b * 4096 + (long)w * 64;  // first permuted row of strip

  f16* qs = shp[wave];
  f16* ks = shp[wave] + 2560;
  f16* vt = shp[wave] + 5120;
  f16* ps = shp[wave];
  const float qscale = 0.17677669529663687f;  // 32^-0.5

  // parked normalized O: ph{h}[i*4+r] packs dims (ln, 16+ln) of row i*16+quad*4+r
  f16x2 ph0[16], ph1[16], ph2[16];

  for (int hi = 0; hi < 3; ++hi) {
    const int hh = wave * 3 + hi;
#pragma unroll
    for (int r = 0; r < 4; ++r) {
      int flat = r * 64 + lane;
      int l = flat >> 2, dg = (flat & 3) * 8;
      long ta = (sbase + l) * 1152 + hh * 32 + dg;
      f16x8 qv = *(const f16x8*)&qkv[ta];
      f16x8 kv = *(const f16x8*)&qkv[ta + 384];
      f16x8 vv = *(const f16x8*)&qkv[ta + 768];
#pragma unroll
      for (int ii = 0; ii < 8; ++ii) qv[ii] = (f16)((float)qv[ii] * qscale);
      *(f16x8*)&qs[l * 40 + dg] = qv;
      *(f16x8*)&ks[l * 40 + dg] = kv;
      // vt XOR-swizzled scalar stores (R11-verified): col' = ((l>>3)^(dg>>3))*8 | (l&7)
      int g = l >> 3, o = l & 7, sw = dg >> 3;
#pragma unroll
      for (int ii = 0; ii < 8; ++ii)
        vt[(dg + ii) * 72 + (((g ^ sw) << 3) | o)] = vv[ii];
    }
    // S = Q K^T (64x64, K=32)
    f16x8 aq[4], bk[4];
#pragma unroll
    for (int i = 0; i < 4; ++i) aq[i] = *(const f16x8*)&qs[(i * 16 + ln) * 40 + q8];
#pragma unroll
    for (int j = 0; j < 4; ++j) bk[j] = *(const f16x8*)&ks[(j * 16 + ln) * 40 + q8];
    f32x4 sc[4][4] = {};
    __builtin_amdgcn_s_setprio(1);
#pragma unroll
    for (int i = 0; i < 4; ++i)
#pragma unroll
      for (int j = 0; j < 4; ++j) sc[i][j] = mfma_16x16x32(aq[i], bk[j], sc[i][j]);
    __builtin_amdgcn_s_setprio(0);

    // softmax rows; deferred normalization
    float rs[4][4];
#pragma unroll
    for (int i = 0; i < 4; ++i)
#pragma unroll
      for (int r = 0; r < 4; ++r) {
        float m = -1e30f;
#pragma unroll
        for (int j = 0; j < 4; ++j) m = fmaxf(m, sc[i][j][r]);
#pragma unroll
        for (int off = 1; off < 16; off <<= 1) m = fmaxf(m, __shfl_xor(m, off, 64));
        float sum = 0.f;
#pragma unroll
        for (int j = 0; j < 4; ++j) {
          float p = __expf(sc[i][j][r] - m);
          sc[i][j][r] = p;
          sum += p;
        }
#pragma unroll
        for (int off = 1; off < 16; off <<= 1) sum += __shfl_xor(sum, off, 64);
        rs[i][r] = 1.0f / sum;
      }

    // P -> ps (overlays qs/ks; same-wave in-order DS after aq/bk reads)
#pragma unroll
    for (int i = 0; i < 4; ++i)
#pragma unroll
      for (int j = 0; j < 4; ++j)
#pragma unroll
        for (int r = 0; r < 4; ++r)
          ps[(i * 16 + quad * 4 + r) * 72 + j * 16 + ln] = (f16)sc[i][j][r];

    // O = P V (64x32, K=64); vt reads use matching swizzle
    f32x4 oc[4][2] = {};
#pragma unroll
    for (int k2 = 0; k2 < 2; ++k2) {
      f16x8 ap[4], bv[2];
#pragma unroll
      for (int i = 0; i < 4; ++i)
        ap[i] = *(const f16x8*)&ps[(i * 16 + ln) * 72 + k2 * 32 + q8];
#pragma unroll
      for (int j = 0; j < 2; ++j) {
        int dimj = j * 16 + ln;
        bv[j] = *(const f16x8*)&vt[dimj * 72 +
                                   (((k2 * 4 + quad) ^ (dimj >> 3)) << 3)];
      }
      __builtin_amdgcn_s_setprio(1);
#pragma unroll
      for (int i = 0; i < 4; ++i)
#pragma unroll
        for (int j = 0; j < 2; ++j) oc[i][j] = mfma_16x16x32(ap[i], bv[j], oc[i][j]);
      __builtin_amdgcn_s_setprio(0);
    }

    // normalize + park (static indices; hi branch is wave-uniform)
#pragma unroll
    for (int i = 0; i < 4; ++i)
#pragma unroll
      for (int r = 0; r < 4; ++r) {
        f16x2 pk;
        pk[0] = (f16)(oc[i][0][r] * rs[i][r]);
        pk[1] = (f16)(oc[i][1][r] * rs[i][r]);
        if (hi == 0) ph0[i * 4 + r] = pk;
        else if (hi == 1) ph1[i * 4 + r] = pk;
        else ph2[i * 4 + r] = pk;
      }
  }

  // ---------------- phase 2: proj ----------------
#define WRITECHUNK(BI, PH)                                        \
  {                                                               \
    _Pragma("unroll") for (int i = 0; i < 4; ++i)                 \
        _Pragma("unroll") for (int r = 0; r < 4; ++r) {           \
      int row = i * 16 + quad * 4 + r;                            \
      aschunk[BI][row * 40 + ln] = PH[i * 4 + r][0];              \
      aschunk[BI][row * 40 + 16 + ln] = PH[i * 4 + r][1];         \
    }                                                             \
  }

  // stage lepe chunk 0: block-wide 256x16B = 64 rows x 64B, source pre-swizzled
  {
    int row = threadIdx.x >> 2, g = threadIdx.x & 3;
    gl_lds16(&lepe16[(sbase + row) * 384 + ((g ^ (row & 3)) * 8)],
             &lbuf[0][0] + (size_t)threadIdx.x * 8);
  }
  if (wave == 0) WRITECHUNK(0, ph0);
  __syncthreads();  // drains lepe stage + aschunk writes

  f32x4 pacc[4][6] = {};
  const int ncol0 = wave * 96;
#pragma unroll
  for (int c = 0; c < 12; ++c) {
    const int cb = c & 1;
    if (c + 1 < 12) {
      // prefetch next lepe panel (async, zero VGPR; lands by next barrier)
      int row = threadIdx.x >> 2, g = threadIdx.x & 3;
      gl_lds16(&lepe16[(sbase + row) * 384 + (c + 1) * 32 + ((g ^ (row & 3)) * 8)],
               &lbuf[cb ^ 1][0] + (size_t)threadIdx.x * 8);
      if ((c + 1) / 3 == wave) {
        const int h = (c + 1) % 3;  // unroll-constant -> static array choice
        if (h == 0) WRITECHUNK(cb ^ 1, ph0)
        else if (h == 1) WRITECHUNK(cb ^ 1, ph1)
        else WRITECHUNK(cb ^ 1, ph2)
      }
    }
    const f16* ac = aschunk[cb];
    f16x8 afr[4], bfr[6];
#pragma unroll
    for (int i = 0; i < 4; ++i) {
      int R = i * 16 + ln;
      f16x8 av = *(const f16x8*)&ac[R * 40 + q8];
      f16x8 lv = *(const f16x8*)&lbuf[cb][R * 32 + ((quad ^ (R & 3)) * 8)];
      afr[i] = av + lv;
    }
#pragma unroll
    for (int j = 0; j < 6; ++j)
      bfr[j] = *(const f16x8*)&pw[(long)(ncol0 + j * 16 + ln) * 384 + c * 32 + q8];
    __builtin_amdgcn_s_setprio(1);
#pragma unroll
    for (int i = 0; i < 4; ++i)
#pragma unroll
      for (int j = 0; j < 6; ++j)
        pacc[i][j] = mfma_16x16x32(afr[i], bfr[j], pacc[i][j]);
    __builtin_amdgcn_s_setprio(0);
    __syncthreads();
  }
#undef WRITECHUNK

  // epilogue: 2 passes of 32 rows; LDS transpose (overlay shp) + float4 + bias
  float* ebuf = (float*)&shp[0][0];  // 32 x 388 f32 = 49664 B <= 59392
#pragma unroll
  for (int p = 0; p < 2; ++p) {
    __syncthreads();
#pragma unroll
    for (int ii = 0; ii < 2; ++ii)
#pragma unroll
      for (int j = 0; j < 6; ++j)
#pragma unroll
        for (int r = 0; r < 4; ++r)
          ebuf[(ii * 16 + quad * 4 + r) * 388 + ncol0 + j * 16 + ln] =
              pacc[p * 2 + ii][j][r];
    __syncthreads();
#pragma unroll
    for (int it = 0; it < 12; ++it) {
      int flat = it * 256 + threadIdx.x;  // 0..3071
      int row = flat / 96;                // 0..31
      int c4 = flat - row * 96;           // 0..95
      long gr = sbase + p * 32 + row;
      int col = c4 * 4;
      float4 b4 = *(const float4*)&bias[col];
      float4 o = *(const float4*)&ebuf[row * 388 + col];
      o.x += b4.x; o.y += b4.y; o.z += b4.z; o.w += b4.w;
      *(float4*)&outf[gr * 384 + col] = o;
    }
  }
}

// ---------------- launch ----------------
extern "C" void kernel_launch(void* const* d_in, const int* in_sizes, int n_in,
                              void* d_out, int out_size, void* d_ws, size_t ws_size,
                              hipStream_t stream) {
  const float* x = (const float*)d_in[0];
  const float* qkv_w = (const float*)d_in[1];
  const float* proj_w = (const float*)d_in[2];
  const float* proj_b = (const float*)d_in[3];
  const float* lepe_w = (const float*)d_in[4];
  const float* lepe_b = (const float*)d_in[5];
  float* out = (float*)d_out;

  char* ws = (char*)d_ws;
  f16* w16 = (f16*)(ws + 0);              //     884,736 B
  f16* pw16 = (f16*)(ws + 884736);        //     294,912 B
  f16* x16 = (f16*)(ws + 1179648);        //  50,331,648 B
  f16* lepe16 = (f16*)(ws + 51511296);    //  50,331,648 B
  f16* qkv16 = (f16*)(ws + 101842944);    // 150,994,944 B  (total 252,837,888 B)

  k_cvt<<<216, 256, 0, stream>>>(qkv_w, w16, 55296);
  k_cvt<<<72, 256, 0, stream>>>(proj_w, pw16, 18432);
  k_prep<<<12288, 256, 0, stream>>>(x, lepe_w, lepe_b, x16, lepe16);
  k_qkv<<<2304, 512, 0, stream>>>(x16, w16, qkv16);
  k_attnproj<<<1024, 256, 0, stream>>>(qkv16, lepe16, pw16, proj_b, out);
}